// Round 2
// baseline (37.711 us; speedup 1.0000x reference)
//
#include <hip/hip_runtime.h>

constexpr int N_SAMP = 2048;
constexpr int T_DIM  = 256;
constexpr int D_DIM  = 64;
constexpr int NBINS  = 64;

// One block per t (grid = 256 = #CUs). 1024 threads.
// Phase 1: LDS histogram (integer, deterministic) for all 64 d at this t.
// Phase 2: per-block partial loss vs densities (vectorized).
// Phase 3: last-arriving block reduces the 256 partials -> out[0].
__global__ __launch_bounds__(1024) void histo_loss_fused(
    const float* __restrict__ x,      // [N, T, D]
    const float* __restrict__ dens,   // [T, D, NBINS]
    const float* __restrict__ bmin,   // [T, D]
    const float* __restrict__ bmax,   // [T, D]
    float* __restrict__ partial,      // [T]      (d_ws)
    unsigned int* __restrict__ counter, // arrival counter (d_ws + 1024B, memset 0 per call)
    float* __restrict__ out)          // [1]
{
    __shared__ alignas(16) unsigned int hist[D_DIM * NBINS];   // 16 KB
    const int t   = blockIdx.x;
    const int tid = threadIdx.x;

    for (int i = tid; i < D_DIM * NBINS; i += 1024) hist[i] = 0u;

    // Each thread owns 4 consecutive d-columns (d0..d0+3), fixed for all n.
    const int c  = tid & 15;   // which float4 within the 64-float row
    const int r  = tid >> 4;   // row offset within a 64-row chunk
    const int d0 = c * 4;

    const float4 a4 = *reinterpret_cast<const float4*>(bmin + t * D_DIM + d0);
    const float4 b4 = *reinterpret_cast<const float4*>(bmax + t * D_DIM + d0);
    const float a[4] = {a4.x, a4.y, a4.z, a4.w};
    const float b[4] = {b4.x, b4.y, b4.z, b4.w};
    float s[4];
#pragma unroll
    for (int j = 0; j < 4; ++j) s[j] = (float)NBINS / (b[j] - a[j]);

    __syncthreads();

    const float4* __restrict__ x4 = reinterpret_cast<const float4*>(x);
    const size_t row4 = (size_t)(T_DIM * D_DIM / 4);         // 4096 float4 per n
    const size_t base = (size_t)r * row4 + (size_t)t * (D_DIM / 4) + (size_t)c;

#pragma unroll 4
    for (int it = 0; it < N_SAMP / 64; ++it) {
        float4 v4 = x4[base + (size_t)it * 64 * row4];
        float v[4] = {v4.x, v4.y, v4.z, v4.w};
#pragma unroll
        for (int j = 0; j < 4; ++j) {
            float vv = v[j];
            if (vv >= a[j] && vv <= b[j]) {
                // in-range => (vv-a) >= 0, so (int) truncation == floor
                int idx = (int)((vv - a[j]) * s[j]);
                idx = idx > NBINS - 1 ? NBINS - 1 : idx;
                atomicAdd(&hist[(d0 + j) * NBINS + idx], 1u);
            }
        }
    }
    __syncthreads();

    // Phase 2: partial loss for this t (4096 terms, 4 per thread, vectorized)
    const float invN = 1.0f / (float)N_SAMP;
    const float* __restrict__ db = dens + (size_t)t * (D_DIM * NBINS);
    const int f = tid * 4;
    float4 dv = *reinterpret_cast<const float4*>(db + f);
    uint4  hv = *reinterpret_cast<const uint4*>(hist + f);
    float sum = fabsf((float)hv.x * invN - dv.x)
              + fabsf((float)hv.y * invN - dv.y)
              + fabsf((float)hv.z * invN - dv.z)
              + fabsf((float)hv.w * invN - dv.w);
#pragma unroll
    for (int off = 32; off > 0; off >>= 1) sum += __shfl_down(sum, off, 64);

    __shared__ float wpart[16];
    if ((tid & 63) == 0) wpart[tid >> 6] = sum;
    __syncthreads();

    __shared__ bool isLast;
    if (tid == 0) {
        float v = 0.0f;
#pragma unroll
        for (int w = 0; w < 16; ++w) v += wpart[w];
        // device-scope release store of this block's partial
        __hip_atomic_store(&partial[t], v, __ATOMIC_RELEASE, __HIP_MEMORY_SCOPE_AGENT);
        unsigned int prev = __hip_atomic_fetch_add(counter, 1u, __ATOMIC_ACQ_REL,
                                                   __HIP_MEMORY_SCOPE_AGENT);
        isLast = (prev == (unsigned int)(T_DIM - 1));
    }
    __syncthreads();

    // Phase 3: last block reduces all 256 partials (fixed order => deterministic)
    if (isLast) {
        float v = 0.0f;
        if (tid < T_DIM)
            v = __hip_atomic_load(&partial[tid], __ATOMIC_ACQUIRE, __HIP_MEMORY_SCOPE_AGENT);
#pragma unroll
        for (int off = 32; off > 0; off >>= 1) v += __shfl_down(v, off, 64);
        __shared__ float wpart2[16];
        if ((tid & 63) == 0) wpart2[tid >> 6] = v;
        __syncthreads();
        if (tid == 0) {
            float tot = 0.0f;
#pragma unroll
            for (int w = 0; w < 16; ++w) tot += wpart2[w];
            out[0] = tot * (1.0f / (float)(T_DIM * D_DIM * NBINS));
        }
    }
}

extern "C" void kernel_launch(void* const* d_in, const int* in_sizes, int n_in,
                              void* d_out, int out_size, void* d_ws, size_t ws_size,
                              hipStream_t stream)
{
    const float* x    = (const float*)d_in[0];   // x_fake  [N,T,D]
    const float* dens = (const float*)d_in[1];   // densities [T,D,NBINS]
    const float* bmin = (const float*)d_in[2];   // [T,D]
    const float* bmax = (const float*)d_in[3];   // [T,D]
    float* out     = (float*)d_out;
    float* partial = (float*)d_ws;                               // 256 floats
    unsigned int* counter = (unsigned int*)((char*)d_ws + 1024); // 4 bytes

    hipMemsetAsync(counter, 0, sizeof(unsigned int), stream);
    histo_loss_fused<<<T_DIM, 1024, 0, stream>>>(x, dens, bmin, bmax,
                                                 partial, counter, out);
}

// Round 3
// 32.127 us; speedup vs baseline: 1.1738x; 1.1738x over previous
//
#include <hip/hip_runtime.h>

constexpr int N_SAMP = 2048;
constexpr int T_DIM  = 256;
constexpr int D_DIM  = 64;
constexpr int NBINS  = 64;

// Fixed-point scale for deterministic cross-block accumulation.
#define FIX_SCALE 16777216.0f   // 2^24
#define CNT_SHIFT 48
#define SUM_MASK  ((1ull << CNT_SHIFT) - 1ull)

// One block per t (grid = 256 = #CUs). 1024 threads.
// Phase 1: LDS integer histogram for all 64 d at this t (deterministic).
// Phase 2: per-block partial loss vs densities (vectorized).
// Phase 3: single packed relaxed atomicAdd {count|fixed_sum}; the block that
//          observes count==T-1 in the returned old value owns the total and
//          writes out[0]. No fences, no acquire loads, fully deterministic
//          (integer adds are order-independent).
__global__ __launch_bounds__(1024) void histo_loss_fused(
    const float* __restrict__ x,      // [N, T, D]
    const float* __restrict__ dens,   // [T, D, NBINS]
    const float* __restrict__ bmin,   // [T, D]
    const float* __restrict__ bmax,   // [T, D]
    unsigned long long* __restrict__ acc, // packed accumulator (memset 0 per call)
    float* __restrict__ out)          // [1]
{
    __shared__ alignas(16) unsigned int hist[D_DIM * NBINS];   // 16 KB
    const int t   = blockIdx.x;
    const int tid = threadIdx.x;

    for (int i = tid; i < D_DIM * NBINS; i += 1024) hist[i] = 0u;

    // Each thread owns 4 consecutive d-columns (d0..d0+3), fixed for all n.
    const int c  = tid & 15;   // which float4 within the 64-float row
    const int r  = tid >> 4;   // row offset within a 64-row chunk
    const int d0 = c * 4;

    const float4 a4 = *reinterpret_cast<const float4*>(bmin + t * D_DIM + d0);
    const float4 b4 = *reinterpret_cast<const float4*>(bmax + t * D_DIM + d0);
    const float a[4] = {a4.x, a4.y, a4.z, a4.w};
    const float b[4] = {b4.x, b4.y, b4.z, b4.w};
    float s[4];
#pragma unroll
    for (int j = 0; j < 4; ++j) s[j] = (float)NBINS / (b[j] - a[j]);

    __syncthreads();

    const float4* __restrict__ x4 = reinterpret_cast<const float4*>(x);
    const size_t row4 = (size_t)(T_DIM * D_DIM / 4);         // 4096 float4 per n
    const size_t base = (size_t)r * row4 + (size_t)t * (D_DIM / 4) + (size_t)c;

#pragma unroll 4
    for (int it = 0; it < N_SAMP / 64; ++it) {
        float4 v4 = x4[base + (size_t)it * 64 * row4];
        float v[4] = {v4.x, v4.y, v4.z, v4.w};
#pragma unroll
        for (int j = 0; j < 4; ++j) {
            float vv = v[j];
            if (vv >= a[j] && vv <= b[j]) {
                // in-range => (vv-a[j]) >= 0, so int truncation == floor
                int idx = (int)((vv - a[j]) * s[j]);
                idx = idx > NBINS - 1 ? NBINS - 1 : idx;
                atomicAdd(&hist[(d0 + j) * NBINS + idx], 1u);
            }
        }
    }
    __syncthreads();

    // Phase 2: partial loss for this t (4096 terms, 4 per thread, vectorized)
    const float invN = 1.0f / (float)N_SAMP;
    const float* __restrict__ db = dens + (size_t)t * (D_DIM * NBINS);
    const int f = tid * 4;
    float4 dv = *reinterpret_cast<const float4*>(db + f);
    uint4  hv = *reinterpret_cast<const uint4*>(hist + f);
    float sum = fabsf((float)hv.x * invN - dv.x)
              + fabsf((float)hv.y * invN - dv.y)
              + fabsf((float)hv.z * invN - dv.z)
              + fabsf((float)hv.w * invN - dv.w);
#pragma unroll
    for (int off = 32; off > 0; off >>= 1) sum += __shfl_down(sum, off, 64);

    __shared__ float wpart[16];
    if ((tid & 63) == 0) wpart[tid >> 6] = sum;
    __syncthreads();

    if (tid == 0) {
        float v = 0.0f;
#pragma unroll
        for (int w = 0; w < 16; ++w) v += wpart[w];
        // v >= 0 (sum of absolute values); quantize to 2^24 fixed point.
        unsigned long long fixed =
            (unsigned long long)(v * FIX_SCALE + 0.5f);
        unsigned long long pack = (1ull << CNT_SHIFT) + fixed;
        unsigned long long old = atomicAdd(acc, pack);   // relaxed, device scope
        if ((old >> CNT_SHIFT) == (unsigned long long)(T_DIM - 1)) {
            unsigned long long total = (old + pack) & SUM_MASK;
            out[0] = (float)((double)total /
                             ((double)FIX_SCALE * (double)(T_DIM * D_DIM * NBINS)));
        }
    }
}

extern "C" void kernel_launch(void* const* d_in, const int* in_sizes, int n_in,
                              void* d_out, int out_size, void* d_ws, size_t ws_size,
                              hipStream_t stream)
{
    const float* x    = (const float*)d_in[0];   // x_fake  [N,T,D]
    const float* dens = (const float*)d_in[1];   // densities [T,D,NBINS]
    const float* bmin = (const float*)d_in[2];   // [T,D]
    const float* bmax = (const float*)d_in[3];   // [T,D]
    float* out = (float*)d_out;
    unsigned long long* acc = (unsigned long long*)d_ws;

    hipMemsetAsync(acc, 0, sizeof(unsigned long long), stream);
    histo_loss_fused<<<T_DIM, 1024, 0, stream>>>(x, dens, bmin, bmax, acc, out);
}

// Round 4
// 26.748 us; speedup vs baseline: 1.4099x; 1.2011x over previous
//
#include <hip/hip_runtime.h>

constexpr int N_SAMP = 2048;
constexpr int T_DIM  = 256;
constexpr int D_DIM  = 64;
constexpr int NBINS  = 64;

// One block per t (grid = 256 = #CUs), 1024 threads.
// Phase 1: LDS integer histogram for all 64 d at this t (deterministic).
// Phase 2: partial loss vs densities (dens prefetched at kernel entry so the
//          4 MB dens stream hides under phase 1), one float4/uint4 per thread.
__global__ __launch_bounds__(1024) void histo_loss_kernel(
    const float* __restrict__ x,      // [N, T, D]
    const float* __restrict__ dens,   // [T, D, NBINS]
    const float* __restrict__ bmin,   // [T, D]
    const float* __restrict__ bmax,   // [T, D]
    float* __restrict__ partial)      // [T]  (d_ws)
{
    __shared__ alignas(16) unsigned int hist[D_DIM * NBINS];   // 16 KB
    const int t   = blockIdx.x;
    const int tid = threadIdx.x;

    // ---- issue independent prefetches FIRST (no deps on LDS or hist) ----
    const float4 dv = *reinterpret_cast<const float4*>(
        dens + (size_t)t * (D_DIM * NBINS) + tid * 4);

    const int c  = tid & 15;   // which float4 within the 64-float row
    const int r  = tid >> 4;   // row offset within a 64-row chunk
    const int d0 = c * 4;
    const float4 a4 = *reinterpret_cast<const float4*>(bmin + t * D_DIM + d0);
    const float4 b4 = *reinterpret_cast<const float4*>(bmax + t * D_DIM + d0);

    // ---- zero LDS histogram ----
    for (int i = tid; i < D_DIM * NBINS; i += 1024) hist[i] = 0u;

    const float a[4] = {a4.x, a4.y, a4.z, a4.w};
    float s[4];
    {
        const float bb[4] = {b4.x, b4.y, b4.z, b4.w};
#pragma unroll
        for (int j = 0; j < 4; ++j) s[j] = (float)NBINS / (bb[j] - a[j]);
        __syncthreads();

        const float4* __restrict__ x4 = reinterpret_cast<const float4*>(x);
        const size_t row4 = (size_t)(T_DIM * D_DIM / 4);     // 4096 float4 per n
        const size_t base = (size_t)r * row4 + (size_t)t * (D_DIM / 4) + (size_t)c;

#pragma unroll 4
        for (int it = 0; it < N_SAMP / 64; ++it) {
            float4 v4 = x4[base + (size_t)it * 64 * row4];
            float v[4] = {v4.x, v4.y, v4.z, v4.w};
#pragma unroll
            for (int j = 0; j < 4; ++j) {
                float vv = v[j];
                if (vv >= a[j] && vv <= bb[j]) {
                    // in-range => (vv-a[j]) >= 0, so int truncation == floor
                    int idx = (int)((vv - a[j]) * s[j]);
                    idx = idx > NBINS - 1 ? NBINS - 1 : idx;
                    atomicAdd(&hist[(d0 + j) * NBINS + idx], 1u);
                }
            }
        }
    }
    __syncthreads();

    // ---- Phase 2: partial loss (dens already in registers) ----
    const float invN = 1.0f / (float)N_SAMP;
    uint4 hv = *reinterpret_cast<const uint4*>(hist + tid * 4);
    float sum = fabsf((float)hv.x * invN - dv.x)
              + fabsf((float)hv.y * invN - dv.y)
              + fabsf((float)hv.z * invN - dv.z)
              + fabsf((float)hv.w * invN - dv.w);
#pragma unroll
    for (int off = 32; off > 0; off >>= 1) sum += __shfl_down(sum, off, 64);

    __shared__ float wpart[16];
    if ((tid & 63) == 0) wpart[tid >> 6] = sum;
    __syncthreads();
    if (tid < 16) {
        float v = wpart[tid];
#pragma unroll
        for (int off = 8; off > 0; off >>= 1) v += __shfl_down(v, off, 16);
        if (tid == 0) partial[t] = v;
    }
}

// One wave. Lane i reads partial[4i..4i+3]; shuffle tree; lane 0 writes out.
__global__ __launch_bounds__(64) void histo_final_reduce(
    const float* __restrict__ partial, float* __restrict__ out)
{
    const int lane = threadIdx.x;
    float4 p = reinterpret_cast<const float4*>(partial)[lane];
    float v = (p.x + p.y) + (p.z + p.w);
#pragma unroll
    for (int off = 32; off > 0; off >>= 1) v += __shfl_down(v, off, 64);
    if (lane == 0)
        out[0] = v * (1.0f / (float)(T_DIM * D_DIM * NBINS));
}

extern "C" void kernel_launch(void* const* d_in, const int* in_sizes, int n_in,
                              void* d_out, int out_size, void* d_ws, size_t ws_size,
                              hipStream_t stream)
{
    const float* x    = (const float*)d_in[0];   // x_fake  [N,T,D]
    const float* dens = (const float*)d_in[1];   // densities [T,D,NBINS]
    const float* bmin = (const float*)d_in[2];   // [T,D]
    const float* bmax = (const float*)d_in[3];   // [T,D]
    float* out     = (float*)d_out;
    float* partial = (float*)d_ws;               // 256 floats

    histo_loss_kernel<<<T_DIM, 1024, 0, stream>>>(x, dens, bmin, bmax, partial);
    histo_final_reduce<<<1, 64, 0, stream>>>(partial, out);
}